// Round 9
// baseline (162.299 us; speedup 1.0000x reference)
//
#include <hip/hip_runtime.h>

#define D_MODEL 1024
#define HDIM    64
#define BATCH   8
#define SEQ     2048
#define BT      (BATCH*SEQ)
#define NCAT    192

typedef __attribute__((ext_vector_type(8))) short s8v;
typedef __attribute__((ext_vector_type(4))) float f4;

__device__ __forceinline__ unsigned short f2bf(float f){
    unsigned u = __builtin_bit_cast(unsigned, f);
    u += 0x7fffu + ((u >> 16) & 1u);
    return (unsigned short)(u >> 16);
}
__device__ __forceinline__ float bf2f(unsigned short h){
    unsigned u = ((unsigned)h) << 16;
    return __builtin_bit_cast(float, u);
}
__device__ __forceinline__ f4 MFMA(s8v a, s8v b, f4 c){
    return __builtin_amdgcn_mfma_f32_16x16x32_bf16(a, b, c, 0, 0, 0);
}

// ---- kernel 1: W -> Wt[192][1024] bf16 hi/lo (transposed, concatenated q|k|v) ----
__global__ void prep_w_kernel(const float* __restrict__ wq, const float* __restrict__ wk,
                              const float* __restrict__ wv,
                              short* __restrict__ wtH, short* __restrict__ wtL){
    int ncat = blockIdx.x;
    const float* w = (ncat < 64) ? wq : ((ncat < 128) ? wk : wv);
    int n = ncat & 63;
    for (int k = threadIdx.x; k < D_MODEL; k += blockDim.x){
        float f = w[k*HDIM + n];
        unsigned short h = f2bf(f);
        wtH[ncat*D_MODEL + k] = (short)h;
        wtL[ncat*D_MODEL + k] = (short)f2bf(f - bf2f(h));
    }
}

// ---- kernel 2: fused QKV projection — barrier-free, LDS-free ----
// 512 blocks x 4 waves; wave = 16 rows x 96 cols. Fragments read DIRECTLY from
// global (x: one 128B line/row/step; W: L1/L2-resident) into named registers
// with a 2-stage software prefetch. Same hi/lo triple-MFMA numerics as before.
__global__ __launch_bounds__(256) void proj_kernel(
        const float* __restrict__ x,
        const short* __restrict__ wtH, const short* __restrict__ wtL,
        short* __restrict__ qh, short* __restrict__ ql,
        short* __restrict__ kh, short* __restrict__ kl,
        short* __restrict__ vt){
    int tid = threadIdx.x;
    int wid = tid >> 6, lane = tid & 63, g = lane >> 4, ln = lane & 15;
    int wm = wid & 1, wn = wid >> 1;       // wave tile: rows wm*16..+15, cols wn*96..+95
    int m0 = blockIdx.x * 32;

    const float* xrow = x + (size_t)(m0 + wm*16 + ln)*D_MODEL + g*8;
    const short* wbH  = wtH + (size_t)(wn*96 + ln)*D_MODEL + g*8;
    const short* wbL  = wtL + (size_t)(wn*96 + ln)*D_MODEL + g*8;

    f4 acc[6];
#pragma unroll
    for (int i = 0; i < 6; i++) acc[i] = (f4){0.f,0.f,0.f,0.f};

    float4 xa0, xb0, xa1, xb1;
    s8v wh0[6], wl0[6], wh1[6], wl1[6];

#define LOADSTEP(S, K0) { \
    xa##S = *(const float4*)(xrow + (K0)); \
    xb##S = *(const float4*)(xrow + (K0) + 4); \
    _Pragma("unroll") \
    for (int nb = 0; nb < 6; nb++){ \
        wh##S[nb] = *(const s8v*)(wbH + (size_t)nb*16*D_MODEL + (K0)); \
        wl##S[nb] = *(const s8v*)(wbL + (size_t)nb*16*D_MODEL + (K0)); } }

#define COMPSTEP(S) { \
    float fx[8] = {xa##S.x, xa##S.y, xa##S.z, xa##S.w, \
                   xb##S.x, xb##S.y, xb##S.z, xb##S.w}; \
    s8v aH, aL; \
    _Pragma("unroll") \
    for (int j = 0; j < 8; j++){ \
        unsigned short h = f2bf(fx[j]); \
        aH[j] = (short)h; \
        aL[j] = (short)f2bf(fx[j] - bf2f(h)); } \
    _Pragma("unroll") \
    for (int nb = 0; nb < 6; nb++){ \
        acc[nb] = MFMA(aH, wh##S[nb], acc[nb]); \
        acc[nb] = MFMA(aL, wh##S[nb], acc[nb]); \
        acc[nb] = MFMA(aH, wl##S[nb], acc[nb]); } }

    LOADSTEP(0, 0)
    for (int k0 = 0; k0 < D_MODEL - 64; k0 += 64){
        LOADSTEP(1, k0 + 32)
        COMPSTEP(0)
        LOADSTEP(0, k0 + 64)
        COMPSTEP(1)
    }
    LOADSTEP(1, D_MODEL - 32)
    COMPSTEP(0)
    COMPSTEP(1)
#undef LOADSTEP
#undef COMPSTEP

#pragma unroll
    for (int nb = 0; nb < 6; nb++){
        int ncat = wn*96 + nb*16 + ln;
        int mat = ncat >> 6, h = ncat & 63;
#pragma unroll
        for (int r = 0; r < 4; r++){
            size_t trow = (size_t)m0 + wm*16 + g*4 + r;
            float v = acc[nb][r];
            unsigned short hh = f2bf(v);
            if (mat == 0){
                qh[trow*HDIM + h] = (short)hh;
                ql[trow*HDIM + h] = (short)f2bf(v - bf2f(hh));
            } else if (mat == 1){
                kh[trow*HDIM + h] = (short)hh;
                kl[trow*HDIM + h] = (short)f2bf(v - bf2f(hh));
            } else {
                size_t bb = trow >> 11, t = trow & 2047;
                vt[((bb*HDIM + h) << 11) + t] = (short)hh;
            }
        }
    }
}

// ---- kernel 3: causal flash attention, in-block KV-split, KVBLK=64 ----
// One block = one 16-row Q strip; wave w owns KV tiles w, w+4, ... (64 keys each)
// with private (o, m, l); partials merged in LDS at block end (exact algebra).
// qi swizzle pairs strip x with 127-x on the same CU -> constant per-CU work.
__global__ __launch_bounds__(256, 4) void attn_kernel(
        const short* __restrict__ qh, const short* __restrict__ ql,
        const short* __restrict__ kh, const short* __restrict__ kl,
        const short* __restrict__ vt, float* __restrict__ out){
    __shared__ unsigned short plds[4][16][112];  // wave-private P tiles (stride 224B: 24-word bank pattern)
    __shared__ float olds[4][16][65];            // partial O, stride 65 = conflict-free
    __shared__ float mlds[4][16], llds[4][16];
    const float SC = 0.125f * 1.44269504088896340736f;  // 1/sqrt(64) * log2(e)
    int tid = threadIdx.x;
    int w = tid >> 6, lane = tid & 63, g = lane >> 4, ln = lane & 15;
    int b = blockIdx.y;
    // balance swizzle: CU gets y parity-spaced blocks -> qi alternates x / 127-x
    int qi = ((blockIdx.y >> 1) & 1) ? (int)(gridDim.x - 1 - blockIdx.x) : (int)blockIdx.x;
    int tq = qi * 16;

    // all 4 waves load the same 16-row Q strip (hi/lo)
    size_t qoff = ((size_t)b*SEQ + tq + ln) * HDIM + g*8;
    s8v q0h = *(const s8v*)(qh + qoff);
    s8v q1h = *(const s8v*)(qh + qoff + 32);
    s8v q0l = *(const s8v*)(ql + qoff);
    s8v q1l = *(const s8v*)(ql + qoff + 32);

    f4 o0 = {0.f,0.f,0.f,0.f}, o1 = o0, o2 = o0, o3 = o0;
    float m[4], lsum[4];   // lsum: PER-LANE partial (deferred reduce after loop)
#pragma unroll
    for (int r = 0; r < 4; r++){ m[r] = -__builtin_inff(); lsum[r] = 0.f; }

    int ntiles = (tq + 79) >> 6;   // ceil((tq+16)/64)
    for (int ti = w; ti < ntiles; ti += 4){
        int s0 = ti << 6;
        size_t kbase = ((size_t)b*SEQ + s0 + ln) * HDIM + g*8;
        f4 z0, z1, z2, z3;
#define QK_SUBTILE(ZJ, J) { \
        const short* kph = kh + kbase + (J)*16*HDIM; \
        const short* kpl = kl + kbase + (J)*16*HDIM; \
        s8v k0h = *(const s8v*)(kph); \
        s8v k1h = *(const s8v*)(kph + 32); \
        s8v k0l = *(const s8v*)(kpl); \
        s8v k1l = *(const s8v*)(kpl + 32); \
        f4 s = {0.f,0.f,0.f,0.f}; \
        s = MFMA(q0h, k0h, s); s = MFMA(q1h, k1h, s); \
        s = MFMA(q0l, k0h, s); s = MFMA(q1l, k1h, s); \
        s = MFMA(q0h, k0l, s); s = MFMA(q1h, k1l, s); \
        ZJ[0] = s[0]*SC; ZJ[1] = s[1]*SC; ZJ[2] = s[2]*SC; ZJ[3] = s[3]*SC; }
        QK_SUBTILE(z0, 0)
        QK_SUBTILE(z1, 1)
        QK_SUBTILE(z2, 2)
        QK_SUBTILE(z3, 3)
#undef QK_SUBTILE
        if (s0 + 63 > tq){   // causal mask (near-diagonal tiles only)
#pragma unroll
            for (int r = 0; r < 4; r++){
                int t = tq + g*4 + r;
                if (s0      + ln > t) z0[r] = -__builtin_inff();
                if (s0 + 16 + ln > t) z1[r] = -__builtin_inff();
                if (s0 + 32 + ln > t) z2[r] = -__builtin_inff();
                if (s0 + 48 + ln > t) z3[r] = -__builtin_inff();
            }
        }
        float al[4];
#pragma unroll
        for (int r = 0; r < 4; r++){
            float v = fmaxf(fmaxf(z0[r], z1[r]), fmaxf(z2[r], z3[r]));
            v = fmaxf(v, __shfl_xor(v, 1));
            v = fmaxf(v, __shfl_xor(v, 2));
            v = fmaxf(v, __shfl_xor(v, 4));
            v = fmaxf(v, __shfl_xor(v, 8));
            float mn = fmaxf(m[r], v);
            al[r] = __builtin_amdgcn_exp2f(m[r] - mn);
            float p0 = __builtin_amdgcn_exp2f(z0[r] - mn);
            float p1 = __builtin_amdgcn_exp2f(z1[r] - mn);
            float p2 = __builtin_amdgcn_exp2f(z2[r] - mn);
            float p3 = __builtin_amdgcn_exp2f(z3[r] - mn);
            lsum[r] = lsum[r]*al[r] + ((p0 + p1) + (p2 + p3));  // lane-partial, no shfl
            m[r] = mn;
            int row = g*4 + r;
            plds[w][row][ln]      = f2bf(p0);
            plds[w][row][ln + 16] = f2bf(p1);
            plds[w][row][ln + 32] = f2bf(p2);
            plds[w][row][ln + 48] = f2bf(p3);
        }
#pragma unroll
        for (int r = 0; r < 4; r++){
            o0[r] *= al[r]; o1[r] *= al[r]; o2[r] *= al[r]; o3[r] *= al[r];
        }
        asm volatile("s_waitcnt lgkmcnt(0)" ::: "memory");  // cross-lane P write->read
        __builtin_amdgcn_sched_barrier(0);
        s8v pa0 = *(const s8v*)&plds[w][ln][g*8];
        s8v pa1 = *(const s8v*)&plds[w][ln][32 + g*8];
        size_t voff = ((size_t)b*HDIM + ln) * SEQ + s0 + g*8;
        s8v v00 = *(const s8v*)(vt + voff);
        s8v v01 = *(const s8v*)(vt + voff + 32);
        s8v v10 = *(const s8v*)(vt + voff + 16*SEQ);
        s8v v11 = *(const s8v*)(vt + voff + 16*SEQ + 32);
        s8v v20 = *(const s8v*)(vt + voff + 32*SEQ);
        s8v v21 = *(const s8v*)(vt + voff + 32*SEQ + 32);
        s8v v30 = *(const s8v*)(vt + voff + 48*SEQ);
        s8v v31 = *(const s8v*)(vt + voff + 48*SEQ + 32);
        o0 = MFMA(pa0, v00, o0); o0 = MFMA(pa1, v01, o0);
        o1 = MFMA(pa0, v10, o1); o1 = MFMA(pa1, v11, o1);
        o2 = MFMA(pa0, v20, o2); o2 = MFMA(pa1, v21, o2);
        o3 = MFMA(pa0, v30, o3); o3 = MFMA(pa1, v31, o3);
    }

    // deferred l-sum reduce (once per wave, off the per-tile critical path)
#pragma unroll
    for (int r = 0; r < 4; r++){
        float s = lsum[r];
        s += __shfl_xor(s, 1);
        s += __shfl_xor(s, 2);
        s += __shfl_xor(s, 4);
        s += __shfl_xor(s, 8);
        lsum[r] = s;
    }

    // ---- write per-wave partials to LDS ----
#pragma unroll
    for (int r = 0; r < 4; r++){
        int row = g*4 + r;
        olds[w][row][ln]      = o0[r];
        olds[w][row][ln + 16] = o1[r];
        olds[w][row][ln + 32] = o2[r];
        olds[w][row][ln + 48] = o3[r];
        if (ln == 0){ mlds[w][row] = m[r]; llds[w][row] = lsum[r]; }
    }
    __syncthreads();

    // ---- combine 4 partials (exact online-softmax merge), coalesced store ----
    {
        int row = tid >> 4;          // 0..15
        int hb  = tid & 15;          // 0..15
        float m0 = mlds[0][row], m1 = mlds[1][row], m2 = mlds[2][row], m3 = mlds[3][row];
        float M = fmaxf(fmaxf(m0, m1), fmaxf(m2, m3));   // finite: wave 0 always has tile 0
        float w0 = __builtin_amdgcn_exp2f(m0 - M);
        float w1 = __builtin_amdgcn_exp2f(m1 - M);
        float w2 = __builtin_amdgcn_exp2f(m2 - M);
        float w3 = __builtin_amdgcn_exp2f(m3 - M);
        float L = llds[0][row]*w0 + llds[1][row]*w1 + llds[2][row]*w2 + llds[3][row]*w3;
        float inv = 1.0f / L;
        size_t obase = ((size_t)b*SEQ + tq + row) * HDIM + hb;
#pragma unroll
        for (int j = 0; j < 4; j++){
            int h = hb + 16*j;
            float acc = olds[0][row][h]*w0 + olds[1][row][h]*w1
                      + olds[2][row][h]*w2 + olds[3][row][h]*w3;
            out[obase + 16*j] = acc * inv;
        }
    }
}

extern "C" void kernel_launch(void* const* d_in, const int* in_sizes, int n_in,
                              void* d_out, int out_size, void* d_ws, size_t ws_size,
                              hipStream_t stream) {
    (void)in_sizes; (void)n_in; (void)out_size; (void)ws_size;
    const float* x  = (const float*)d_in[0];
    const float* wq = (const float*)d_in[1];
    const float* wk = (const float*)d_in[2];
    const float* wv = (const float*)d_in[3];
    float* out = (float*)d_out;

    short* ws  = (short*)d_ws;               // ~11.3 MB total workspace
    short* wtH = ws;
    short* wtL = wtH + (size_t)NCAT*D_MODEL;
    short* qh  = wtL + (size_t)NCAT*D_MODEL;
    short* ql  = qh + (size_t)BT*HDIM;
    short* kh  = ql + (size_t)BT*HDIM;
    short* kl  = kh + (size_t)BT*HDIM;
    short* vt  = kl + (size_t)BT*HDIM;

    prep_w_kernel<<<NCAT, 256, 0, stream>>>(wq, wk, wv, wtH, wtL);
    proj_kernel<<<BT/32, 256, 0, stream>>>(x, wtH, wtL, qh, ql, kh, kl, vt);
    attn_kernel<<<dim3(SEQ/16, BATCH), 256, 0, stream>>>(qh, ql, kh, kl, vt, out);
}

// Round 10
// 91.972 us; speedup vs baseline: 1.7647x; 1.7647x over previous
//
#include <hip/hip_runtime.h>

#define D_MODEL 1024
#define HDIM    64
#define BATCH   8
#define SEQ     2048
#define BT      (BATCH*SEQ)
#define NCAT    192
#define KSTEP   32
#define NKS     (D_MODEL/KSTEP)          // 32 k-steps
#define NFRAG   24                       // 12 hi + 12 lo subtiles of 16 cols
#define FRAGSH  512                      // shorts per frag: 64 lanes x 8
#define STEPSH  (NFRAG*FRAGSH)           // 12288 shorts per k-step

typedef __attribute__((ext_vector_type(8))) short s8v;
typedef __attribute__((ext_vector_type(4))) float f4;
typedef __attribute__((ext_vector_type(4))) unsigned short u16x4;

__device__ __forceinline__ unsigned short f2bf(float f){
    unsigned u = __builtin_bit_cast(unsigned, f);
    u += 0x7fffu + ((u >> 16) & 1u);
    return (unsigned short)(u >> 16);
}
__device__ __forceinline__ float bf2f(unsigned short h){
    unsigned u = ((unsigned)h) << 16;
    return __builtin_bit_cast(float, u);
}
__device__ __forceinline__ f4 MFMA(s8v a, s8v b, f4 c){
    return __builtin_amdgcn_mfma_f32_16x16x32_bf16(a, b, c, 0, 0, 0);
}

// ---- kernel 1: W -> fragment-packed Wt ----
// wtP layout: [kstep t1][frag f][lane l][e] shorts, l = g*16+ln, e = k&7.
// frag f<12: hi of col-subtile nb=f; f>=12: lo of nb=f-12.
// MFMA b-frag for subtile nb, kstep t1 is then 64 consecutive 16B lane-slots.
__global__ void prep_w_kernel(const float* __restrict__ wq, const float* __restrict__ wk,
                              const float* __restrict__ wv,
                              short* __restrict__ wtP){
    int ncat = blockIdx.x;
    const float* w = (ncat < 64) ? wq : ((ncat < 128) ? wk : wv);
    int n  = ncat & 63;
    int nb = ncat >> 4, ln = ncat & 15;
    for (int k = threadIdx.x; k < D_MODEL; k += blockDim.x){
        float f = w[k*HDIM + n];
        unsigned short h = f2bf(f);
        unsigned short l = f2bf(f - bf2f(h));
        int t1 = k >> 5, g = (k >> 3) & 3, e = k & 7;
        size_t base = (size_t)t1*STEPSH + (size_t)((g*16 + ln) << 3) + e;
        wtP[base + (size_t)nb*FRAGSH]        = (short)h;
        wtP[base + (size_t)(12 + nb)*FRAGSH] = (short)l;
    }
}

// ---- kernel 2: fused QKV projection, LDS-staged + issue-early pipeline ----
// 512 blocks x 4 waves (2 blocks/CU = 2 barrier domains). Block tile 32x192,
// wave tile 16x96. W frags conflict-free (lane-major packed); loads for step
// t+1 issued before COMPUTE(t) so HBM/L2 latency hides under MFMA+ds_read.
__global__ __launch_bounds__(256) void proj_kernel(
        const float* __restrict__ x,
        const short* __restrict__ wtP,
        short* __restrict__ qh, short* __restrict__ ql,
        short* __restrict__ kh, short* __restrict__ kl,
        short* __restrict__ vt){
    __shared__ short xsH[2][32][40], xsL[2][32][40];        // 80B rows: 16B-aligned, 2-way max
    __shared__ __align__(16) short wlds[2][STEPSH];          // frag-packed, conflict-free
    int tid = threadIdx.x;
    int wid = tid >> 6, lane = tid & 63, g = lane >> 4, ln = lane & 15;
    int wm = wid & 1, wn = wid >> 1;    // wave tile: rows wm*16..+15, cols wn*96..+95
    int m0 = blockIdx.x * 32;

    const float* xptr = x + (size_t)(m0 + (tid >> 3))*D_MODEL + (tid & 7)*4;
    const short* wptr = wtP + (size_t)(wid*6)*FRAGSH + (size_t)lane*8;

    f4 acc[6];
#pragma unroll
    for (int i = 0; i < 6; i++) acc[i] = (f4){0.f,0.f,0.f,0.f};

    float4 xr;
    s8v wr0, wr1, wr2, wr3, wr4, wr5;

#define LOADREGS(T) { \
    xr  = *(const float4*)(xptr + (size_t)(T)*KSTEP); \
    const short* wp = wptr + (size_t)(T)*STEPSH; \
    wr0 = *(const s8v*)(wp);            wr1 = *(const s8v*)(wp + 1*FRAGSH); \
    wr2 = *(const s8v*)(wp + 2*FRAGSH); wr3 = *(const s8v*)(wp + 3*FRAGSH); \
    wr4 = *(const s8v*)(wp + 4*FRAGSH); wr5 = *(const s8v*)(wp + 5*FRAGSH); }

#define STORE_STAGE(B) { \
    int row = tid >> 3, kc = (tid & 7) << 2; \
    float f0 = xr.x, f1 = xr.y, f2 = xr.z, f3 = xr.w; \
    unsigned short h0 = f2bf(f0), h1 = f2bf(f1), h2 = f2bf(f2), h3 = f2bf(f3); \
    u16x4 hv, lv; \
    hv[0]=h0; hv[1]=h1; hv[2]=h2; hv[3]=h3; \
    lv[0]=f2bf(f0-bf2f(h0)); lv[1]=f2bf(f1-bf2f(h1)); \
    lv[2]=f2bf(f2-bf2f(h2)); lv[3]=f2bf(f3-bf2f(h3)); \
    *(u16x4*)&xsH[B][row][kc] = hv; \
    *(u16x4*)&xsL[B][row][kc] = lv; \
    short* wd = &wlds[B][(size_t)(wid*6)*FRAGSH + (size_t)lane*8]; \
    *(s8v*)(wd)            = wr0; *(s8v*)(wd + 1*FRAGSH) = wr1; \
    *(s8v*)(wd + 2*FRAGSH) = wr2; *(s8v*)(wd + 3*FRAGSH) = wr3; \
    *(s8v*)(wd + 4*FRAGSH) = wr4; *(s8v*)(wd + 5*FRAGSH) = wr5; }

#define COMPUTE(B) { \
    s8v aH = *(const s8v*)&xsH[B][wm*16 + ln][g*8]; \
    s8v aL = *(const s8v*)&xsL[B][wm*16 + ln][g*8]; \
    _Pragma("unroll") \
    for (int nb = 0; nb < 6; nb++){ \
        s8v bH = *(const s8v*)&wlds[B][(size_t)(wn*6 + nb)*FRAGSH + (size_t)lane*8]; \
        s8v bL = *(const s8v*)&wlds[B][(size_t)(12 + wn*6 + nb)*FRAGSH + (size_t)lane*8]; \
        acc[nb] = MFMA(aH, bH, acc[nb]); \
        acc[nb] = MFMA(aL, bH, acc[nb]); \
        acc[nb] = MFMA(aH, bL, acc[nb]); } }

    // prologue: stage step 0
    LOADREGS(0)
    STORE_STAGE(0)
    __syncthreads();
    for (int t = 0; t < NKS - 1; t++){
        LOADREGS(t + 1)                       // issue-early: VMEM in flight during compute
        __builtin_amdgcn_sched_barrier(0);    // pin loads before the MFMA phase
        COMPUTE(t & 1)
        STORE_STAGE((t + 1) & 1)              // vmcnt wait lands here, after compute
        __syncthreads();
    }
    COMPUTE((NKS - 1) & 1)
#undef LOADREGS
#undef STORE_STAGE
#undef COMPUTE

#pragma unroll
    for (int nb = 0; nb < 6; nb++){
        int ncat = wn*96 + nb*16 + ln;
        int mat = ncat >> 6, h = ncat & 63;
#pragma unroll
        for (int r = 0; r < 4; r++){
            size_t trow = (size_t)m0 + wm*16 + g*4 + r;
            float v = acc[nb][r];
            unsigned short hh = f2bf(v);
            if (mat == 0){
                qh[trow*HDIM + h] = (short)hh;
                ql[trow*HDIM + h] = (short)f2bf(v - bf2f(hh));
            } else if (mat == 1){
                kh[trow*HDIM + h] = (short)hh;
                kl[trow*HDIM + h] = (short)f2bf(v - bf2f(hh));
            } else {
                size_t bb = trow >> 11, t = trow & 2047;
                vt[((bb*HDIM + h) << 11) + t] = (short)hh;
            }
        }
    }
}

// ---- kernel 3: causal flash attention, in-block KV-split, KVBLK=64 ----
// One block = one 16-row Q strip; wave w owns KV tiles w, w+4, ... (64 keys each)
// with private (o, m, l); partials merged in LDS at block end (exact algebra).
// qi swizzle pairs strip x with 127-x on the same CU -> constant per-CU work.
__global__ __launch_bounds__(256, 4) void attn_kernel(
        const short* __restrict__ qh, const short* __restrict__ ql,
        const short* __restrict__ kh, const short* __restrict__ kl,
        const short* __restrict__ vt, float* __restrict__ out){
    __shared__ unsigned short plds[4][16][112];  // wave-private P tiles (stride 224B: 24-word bank pattern)
    __shared__ float olds[4][16][65];            // partial O, stride 65 = conflict-free
    __shared__ float mlds[4][16], llds[4][16];
    const float SC = 0.125f * 1.44269504088896340736f;  // 1/sqrt(64) * log2(e)
    int tid = threadIdx.x;
    int w = tid >> 6, lane = tid & 63, g = lane >> 4, ln = lane & 15;
    int b = blockIdx.y;
    // balance swizzle: CU gets y parity-spaced blocks -> qi alternates x / 127-x
    int qi = ((blockIdx.y >> 1) & 1) ? (int)(gridDim.x - 1 - blockIdx.x) : (int)blockIdx.x;
    int tq = qi * 16;

    // all 4 waves load the same 16-row Q strip (hi/lo)
    size_t qoff = ((size_t)b*SEQ + tq + ln) * HDIM + g*8;
    s8v q0h = *(const s8v*)(qh + qoff);
    s8v q1h = *(const s8v*)(qh + qoff + 32);
    s8v q0l = *(const s8v*)(ql + qoff);
    s8v q1l = *(const s8v*)(ql + qoff + 32);

    f4 o0 = {0.f,0.f,0.f,0.f}, o1 = o0, o2 = o0, o3 = o0;
    float m[4], lsum[4];   // lsum: PER-LANE partial (deferred reduce after loop)
#pragma unroll
    for (int r = 0; r < 4; r++){ m[r] = -__builtin_inff(); lsum[r] = 0.f; }

    int ntiles = (tq + 79) >> 6;   // ceil((tq+16)/64)
    for (int ti = w; ti < ntiles; ti += 4){
        int s0 = ti << 6;
        size_t kbase = ((size_t)b*SEQ + s0 + ln) * HDIM + g*8;
        f4 z0, z1, z2, z3;
#define QK_SUBTILE(ZJ, J) { \
        const short* kph = kh + kbase + (J)*16*HDIM; \
        const short* kpl = kl + kbase + (J)*16*HDIM; \
        s8v k0h = *(const s8v*)(kph); \
        s8v k1h = *(const s8v*)(kph + 32); \
        s8v k0l = *(const s8v*)(kpl); \
        s8v k1l = *(const s8v*)(kpl + 32); \
        f4 s = {0.f,0.f,0.f,0.f}; \
        s = MFMA(q0h, k0h, s); s = MFMA(q1h, k1h, s); \
        s = MFMA(q0l, k0h, s); s = MFMA(q1l, k1h, s); \
        s = MFMA(q0h, k0l, s); s = MFMA(q1h, k1l, s); \
        ZJ[0] = s[0]*SC; ZJ[1] = s[1]*SC; ZJ[2] = s[2]*SC; ZJ[3] = s[3]*SC; }
        QK_SUBTILE(z0, 0)
        QK_SUBTILE(z1, 1)
        QK_SUBTILE(z2, 2)
        QK_SUBTILE(z3, 3)
#undef QK_SUBTILE
        if (s0 + 63 > tq){   // causal mask (near-diagonal tiles only)
#pragma unroll
            for (int r = 0; r < 4; r++){
                int t = tq + g*4 + r;
                if (s0      + ln > t) z0[r] = -__builtin_inff();
                if (s0 + 16 + ln > t) z1[r] = -__builtin_inff();
                if (s0 + 32 + ln > t) z2[r] = -__builtin_inff();
                if (s0 + 48 + ln > t) z3[r] = -__builtin_inff();
            }
        }
        float al[4];
#pragma unroll
        for (int r = 0; r < 4; r++){
            float v = fmaxf(fmaxf(z0[r], z1[r]), fmaxf(z2[r], z3[r]));
            v = fmaxf(v, __shfl_xor(v, 1));
            v = fmaxf(v, __shfl_xor(v, 2));
            v = fmaxf(v, __shfl_xor(v, 4));
            v = fmaxf(v, __shfl_xor(v, 8));
            float mn = fmaxf(m[r], v);
            al[r] = __builtin_amdgcn_exp2f(m[r] - mn);
            float p0 = __builtin_amdgcn_exp2f(z0[r] - mn);
            float p1 = __builtin_amdgcn_exp2f(z1[r] - mn);
            float p2 = __builtin_amdgcn_exp2f(z2[r] - mn);
            float p3 = __builtin_amdgcn_exp2f(z3[r] - mn);
            lsum[r] = lsum[r]*al[r] + ((p0 + p1) + (p2 + p3));  // lane-partial, no shfl
            m[r] = mn;
            int row = g*4 + r;
            plds[w][row][ln]      = f2bf(p0);
            plds[w][row][ln + 16] = f2bf(p1);
            plds[w][row][ln + 32] = f2bf(p2);
            plds[w][row][ln + 48] = f2bf(p3);
        }
#pragma unroll
        for (int r = 0; r < 4; r++){
            o0[r] *= al[r]; o1[r] *= al[r]; o2[r] *= al[r]; o3[r] *= al[r];
        }
        asm volatile("s_waitcnt lgkmcnt(0)" ::: "memory");  // cross-lane P write->read
        __builtin_amdgcn_sched_barrier(0);
        s8v pa0 = *(const s8v*)&plds[w][ln][g*8];
        s8v pa1 = *(const s8v*)&plds[w][ln][32 + g*8];
        size_t voff = ((size_t)b*HDIM + ln) * SEQ + s0 + g*8;
        s8v v00 = *(const s8v*)(vt + voff);
        s8v v01 = *(const s8v*)(vt + voff + 32);
        s8v v10 = *(const s8v*)(vt + voff + 16*SEQ);
        s8v v11 = *(const s8v*)(vt + voff + 16*SEQ + 32);
        s8v v20 = *(const s8v*)(vt + voff + 32*SEQ);
        s8v v21 = *(const s8v*)(vt + voff + 32*SEQ + 32);
        s8v v30 = *(const s8v*)(vt + voff + 48*SEQ);
        s8v v31 = *(const s8v*)(vt + voff + 48*SEQ + 32);
        o0 = MFMA(pa0, v00, o0); o0 = MFMA(pa1, v01, o0);
        o1 = MFMA(pa0, v10, o1); o1 = MFMA(pa1, v11, o1);
        o2 = MFMA(pa0, v20, o2); o2 = MFMA(pa1, v21, o2);
        o3 = MFMA(pa0, v30, o3); o3 = MFMA(pa1, v31, o3);
    }

    // deferred l-sum reduce (once per wave, off the per-tile critical path)
#pragma unroll
    for (int r = 0; r < 4; r++){
        float s = lsum[r];
        s += __shfl_xor(s, 1);
        s += __shfl_xor(s, 2);
        s += __shfl_xor(s, 4);
        s += __shfl_xor(s, 8);
        lsum[r] = s;
    }

    // ---- write per-wave partials to LDS ----
#pragma unroll
    for (int r = 0; r < 4; r++){
        int row = g*4 + r;
        olds[w][row][ln]      = o0[r];
        olds[w][row][ln + 16] = o1[r];
        olds[w][row][ln + 32] = o2[r];
        olds[w][row][ln + 48] = o3[r];
        if (ln == 0){ mlds[w][row] = m[r]; llds[w][row] = lsum[r]; }
    }
    __syncthreads();

    // ---- combine 4 partials (exact online-softmax merge), coalesced store ----
    {
        int row = tid >> 4;          // 0..15
        int hb  = tid & 15;          // 0..15
        float m0 = mlds[0][row], m1 = mlds[1][row], m2 = mlds[2][row], m3 = mlds[3][row];
        float M = fmaxf(fmaxf(m0, m1), fmaxf(m2, m3));   // finite: wave 0 always has tile 0
        float w0 = __builtin_amdgcn_exp2f(m0 - M);
        float w1 = __builtin_amdgcn_exp2f(m1 - M);
        float w2 = __builtin_amdgcn_exp2f(m2 - M);
        float w3 = __builtin_amdgcn_exp2f(m3 - M);
        float L = llds[0][row]*w0 + llds[1][row]*w1 + llds[2][row]*w2 + llds[3][row]*w3;
        float inv = 1.0f / L;
        size_t obase = ((size_t)b*SEQ + tq + row) * HDIM + hb;
#pragma unroll
        for (int j = 0; j < 4; j++){
            int h = hb + 16*j;
            float acc = olds[0][row][h]*w0 + olds[1][row][h]*w1
                      + olds[2][row][h]*w2 + olds[3][row][h]*w3;
            out[obase + 16*j] = acc * inv;
        }
    }
}

extern "C" void kernel_launch(void* const* d_in, const int* in_sizes, int n_in,
                              void* d_out, int out_size, void* d_ws, size_t ws_size,
                              hipStream_t stream) {
    (void)in_sizes; (void)n_in; (void)out_size; (void)ws_size;
    const float* x  = (const float*)d_in[0];
    const float* wq = (const float*)d_in[1];
    const float* wk = (const float*)d_in[2];
    const float* wv = (const float*)d_in[3];
    float* out = (float*)d_out;

    short* ws  = (short*)d_ws;               // ~11.3 MB total workspace
    short* wtP = ws;                         // packed W: 32*12288 shorts = 768 KB
    short* qh  = wtP + (size_t)NKS*STEPSH;
    short* ql  = qh + (size_t)BT*HDIM;
    short* kh  = ql + (size_t)BT*HDIM;
    short* kl  = kh + (size_t)BT*HDIM;
    short* vt  = kl + (size_t)BT*HDIM;

    prep_w_kernel<<<NCAT, 256, 0, stream>>>(wq, wk, wv, wtP);
    proj_kernel<<<BT/32, 256, 0, stream>>>(x, wtP, qh, ql, kh, kl, vt);
    attn_kernel<<<dim3(SEQ/16, BATCH), 256, 0, stream>>>(qh, ql, kh, kl, vt, out);
}

// Round 11
// 68.881 us; speedup vs baseline: 2.3562x; 1.3352x over previous
//
#include <hip/hip_runtime.h>

#define D_MODEL 1024
#define HDIM    64
#define BATCH   8
#define SEQ     2048
#define BT      (BATCH*SEQ)
#define NCAT    192
#define KSTEP   32
#define NKS     (D_MODEL/KSTEP)          // 32 k-steps
#define NFRAG   24                       // 12 hi + 12 lo subtiles of 16 cols
#define FRAGSH  512                      // shorts per frag: 64 lanes x 8
#define STEPSH  (NFRAG*FRAGSH)           // 12288 shorts per k-step

typedef __attribute__((ext_vector_type(8))) short s8v;
typedef __attribute__((ext_vector_type(4))) float f4;
typedef __attribute__((ext_vector_type(4))) unsigned short u16x4;

__device__ __forceinline__ unsigned short f2bf(float f){
    unsigned u = __builtin_bit_cast(unsigned, f);
    u += 0x7fffu + ((u >> 16) & 1u);
    return (unsigned short)(u >> 16);
}
__device__ __forceinline__ float bf2f(unsigned short h){
    unsigned u = ((unsigned)h) << 16;
    return __builtin_bit_cast(float, u);
}
__device__ __forceinline__ f4 MFMA(s8v a, s8v b, f4 c){
    return __builtin_amdgcn_mfma_f32_16x16x32_bf16(a, b, c, 0, 0, 0);
}

// ---- kernel 1: W -> fragment-packed Wt (hi/lo) ----
// wtP layout: [kstep t1][frag f][lane l][e] shorts; f<12: hi of subtile nb=f,
// f>=12: lo of nb=f-12. One frag = 64 lanes x 16B, contiguous 1KB.
__global__ void prep_w_kernel(const float* __restrict__ wq, const float* __restrict__ wk,
                              const float* __restrict__ wv,
                              short* __restrict__ wtP){
    int ncat = blockIdx.x;
    const float* w = (ncat < 64) ? wq : ((ncat < 128) ? wk : wv);
    int n  = ncat & 63;
    int nb = ncat >> 4, ln = ncat & 15;
    for (int k = threadIdx.x; k < D_MODEL; k += blockDim.x){
        float f = w[k*HDIM + n];
        unsigned short h = f2bf(f);
        unsigned short l = f2bf(f - bf2f(h));
        int t1 = k >> 5, g = (k >> 3) & 3, e = k & 7;
        size_t base = (size_t)t1*STEPSH + (size_t)((g*16 + ln) << 3) + e;
        wtP[base + (size_t)nb*FRAGSH]        = (short)h;
        wtP[base + (size_t)(12 + nb)*FRAGSH] = (short)l;
    }
}

// ---- kernel 2: fused QKV projection ----
// 256 blocks x 8 waves; block 64 rows x 192 cols; wave = 32 rows x 48 cols.
// x staged in LDS (double-buffered, 2-step register prefetch from HBM);
// W frags read DIRECTLY global->reg (L1/L2-resident, 2-step double-buffered).
// GEMM stays hi/lo (fp32-accurate); outputs q,k,v single bf16 (v transposed).
__global__ __launch_bounds__(512) void proj_kernel(
        const float* __restrict__ x,
        const short* __restrict__ wtP,
        short* __restrict__ q, short* __restrict__ k,
        short* __restrict__ vt){
    __shared__ short xsH[2][64][40], xsL[2][64][40];    // 20.5 KB total
    int tid = threadIdx.x;
    int wid = tid >> 6, lane = tid & 63, g = lane >> 4, ln = lane & 15;
    int wm = wid >> 2, wn = wid & 3;   // rows wm*32..+31, cols wn*48..+47
    int m0 = blockIdx.x * 64;

    const float* xptr = x + (size_t)(m0 + (tid >> 3))*D_MODEL + (tid & 7)*4;
    const short* wbase = wtP + (size_t)(wn*3)*FRAGSH + (size_t)lane*8;

    f4 acc[6];
#pragma unroll
    for (int i = 0; i < 6; i++) acc[i] = (f4){0.f,0.f,0.f,0.f};

    float4 x0, x1;
    s8v whA0, whA1, whA2, wlA0, wlA1, wlA2;
    s8v whB0, whB1, whB2, wlB0, wlB1, wlB2;

#define LOADX(R, T) { R = *(const float4*)(xptr + (size_t)(T)*KSTEP); }
#define LOADW(S, T) { \
    const short* wp = wbase + (size_t)(T)*STEPSH; \
    wh##S##0 = *(const s8v*)(wp); \
    wh##S##1 = *(const s8v*)(wp + FRAGSH); \
    wh##S##2 = *(const s8v*)(wp + 2*FRAGSH); \
    const short* wp2 = wp + 12*FRAGSH; \
    wl##S##0 = *(const s8v*)(wp2); \
    wl##S##1 = *(const s8v*)(wp2 + FRAGSH); \
    wl##S##2 = *(const s8v*)(wp2 + 2*FRAGSH); }

#define STAGEX(B, R) { \
    int row = tid >> 3, kc = (tid & 7) << 2; \
    float f0 = R.x, f1 = R.y, f2 = R.z, f3 = R.w; \
    unsigned short h0 = f2bf(f0), h1 = f2bf(f1), h2 = f2bf(f2), h3 = f2bf(f3); \
    u16x4 hv, lv; \
    hv[0]=h0; hv[1]=h1; hv[2]=h2; hv[3]=h3; \
    lv[0]=f2bf(f0-bf2f(h0)); lv[1]=f2bf(f1-bf2f(h1)); \
    lv[2]=f2bf(f2-bf2f(h2)); lv[3]=f2bf(f3-bf2f(h3)); \
    *(u16x4*)&xsH[B][row][kc] = hv; \
    *(u16x4*)&xsL[B][row][kc] = lv; }

#define COMPUTE(B, S) { \
    s8v aH0 = *(const s8v*)&xsH[B][wm*32 + ln][g*8]; \
    s8v aL0 = *(const s8v*)&xsL[B][wm*32 + ln][g*8]; \
    s8v aH1 = *(const s8v*)&xsH[B][wm*32 + 16 + ln][g*8]; \
    s8v aL1 = *(const s8v*)&xsL[B][wm*32 + 16 + ln][g*8]; \
    acc[0] = MFMA(aH0, wh##S##0, acc[0]); \
    acc[0] = MFMA(aL0, wh##S##0, acc[0]); \
    acc[0] = MFMA(aH0, wl##S##0, acc[0]); \
    acc[1] = MFMA(aH0, wh##S##1, acc[1]); \
    acc[1] = MFMA(aL0, wh##S##1, acc[1]); \
    acc[1] = MFMA(aH0, wl##S##1, acc[1]); \
    acc[2] = MFMA(aH0, wh##S##2, acc[2]); \
    acc[2] = MFMA(aL0, wh##S##2, acc[2]); \
    acc[2] = MFMA(aH0, wl##S##2, acc[2]); \
    acc[3] = MFMA(aH1, wh##S##0, acc[3]); \
    acc[3] = MFMA(aL1, wh##S##0, acc[3]); \
    acc[3] = MFMA(aH1, wl##S##0, acc[3]); \
    acc[4] = MFMA(aH1, wh##S##1, acc[4]); \
    acc[4] = MFMA(aL1, wh##S##1, acc[4]); \
    acc[4] = MFMA(aH1, wl##S##1, acc[4]); \
    acc[5] = MFMA(aH1, wh##S##2, acc[5]); \
    acc[5] = MFMA(aL1, wh##S##2, acc[5]); \
    acc[5] = MFMA(aH1, wl##S##2, acc[5]); }

    // prologue: x for steps 0,1; W for steps 0,1; stage step 0
    LOADX(x0, 0)
    LOADX(x1, 1)
    LOADW(A, 0)
    LOADW(B, 1)
    STAGEX(0, x0)
    __syncthreads();

    for (int t = 0; t < NKS; t += 2){
        if (t + 2 < NKS) LOADX(x0, t + 2)       // HBM, 2 steps ahead
        COMPUTE(0, A)                            // step t
        if (t + 2 < NKS) LOADW(A, t + 2)         // L2, 2 steps ahead
        STAGEX(1, x1)                            // stage step t+1 (x1 loaded 2 iters ago)
        __syncthreads();
        if (t + 3 < NKS) LOADX(x1, t + 3)
        COMPUTE(1, B)                            // step t+1
        if (t + 3 < NKS) LOADW(B, t + 3)
        if (t + 2 < NKS){ STAGEX(0, x0) }        // stage step t+2
        __syncthreads();
    }
#undef LOADX
#undef LOADW
#undef STAGEX
#undef COMPUTE

    // epilogue: q,k,v single bf16 (GEMM was fp32-accurate; one rounding here)
#pragma unroll
    for (int a = 0; a < 2; a++){
#pragma unroll
        for (int nb = 0; nb < 3; nb++){
            int ncat = wn*48 + nb*16 + ln;
            int mat = ncat >> 6, h = ncat & 63;
#pragma unroll
            for (int r = 0; r < 4; r++){
                size_t trow = (size_t)m0 + wm*32 + a*16 + g*4 + r;
                float v = acc[a*3 + nb][r];
                unsigned short hh = f2bf(v);
                if (mat == 0){
                    q[trow*HDIM + h] = (short)hh;
                } else if (mat == 1){
                    k[trow*HDIM + h] = (short)hh;
                } else {
                    size_t bb = trow >> 11, t = trow & 2047;
                    vt[((bb*HDIM + h) << 11) + t] = (short)hh;
                }
            }
        }
    }
}

// ---- kernel 3: causal flash attention, in-block KV-split, KVBLK=64 ----
// Single-bf16 Q/K (error budget verified); wave w owns KV tiles w, w+4, ...;
// partials merged in LDS at block end. qi swizzle balances per-CU work.
__global__ __launch_bounds__(256, 5) void attn_kernel(
        const short* __restrict__ qg, const short* __restrict__ kg,
        const short* __restrict__ vt, float* __restrict__ out){
    __shared__ unsigned short plds[4][16][112];
    __shared__ float olds[4][16][65];
    __shared__ float mlds[4][16], llds[4][16];
    const float SC = 0.125f * 1.44269504088896340736f;  // 1/sqrt(64) * log2(e)
    int tid = threadIdx.x;
    int w = tid >> 6, lane = tid & 63, g = lane >> 4, ln = lane & 15;
    int b = blockIdx.y;
    int qi = ((blockIdx.y >> 1) & 1) ? (int)(gridDim.x - 1 - blockIdx.x) : (int)blockIdx.x;
    int tq = qi * 16;

    size_t qoff = ((size_t)b*SEQ + tq + ln) * HDIM + g*8;
    s8v q0 = *(const s8v*)(qg + qoff);
    s8v q1 = *(const s8v*)(qg + qoff + 32);

    f4 o0 = {0.f,0.f,0.f,0.f}, o1 = o0, o2 = o0, o3 = o0;
    float m[4], lsum[4];
#pragma unroll
    for (int r = 0; r < 4; r++){ m[r] = -__builtin_inff(); lsum[r] = 0.f; }

    int ntiles = (tq + 79) >> 6;   // ceil((tq+16)/64)
    for (int ti = w; ti < ntiles; ti += 4){
        int s0 = ti << 6;
        size_t kbase = ((size_t)b*SEQ + s0 + ln) * HDIM + g*8;
        f4 z0, z1, z2, z3;
#define QK_SUBTILE(ZJ, J) { \
        const short* kp = kg + kbase + (J)*16*HDIM; \
        s8v k0 = *(const s8v*)(kp); \
        s8v k1 = *(const s8v*)(kp + 32); \
        f4 s = {0.f,0.f,0.f,0.f}; \
        s = MFMA(q0, k0, s); s = MFMA(q1, k1, s); \
        ZJ[0] = s[0]*SC; ZJ[1] = s[1]*SC; ZJ[2] = s[2]*SC; ZJ[3] = s[3]*SC; }
        QK_SUBTILE(z0, 0)
        QK_SUBTILE(z1, 1)
        QK_SUBTILE(z2, 2)
        QK_SUBTILE(z3, 3)
#undef QK_SUBTILE
        if (s0 + 63 > tq){   // causal mask (near-diagonal tiles only)
#pragma unroll
            for (int r = 0; r < 4; r++){
                int t = tq + g*4 + r;
                if (s0      + ln > t) z0[r] = -__builtin_inff();
                if (s0 + 16 + ln > t) z1[r] = -__builtin_inff();
                if (s0 + 32 + ln > t) z2[r] = -__builtin_inff();
                if (s0 + 48 + ln > t) z3[r] = -__builtin_inff();
            }
        }
        float al[4];
#pragma unroll
        for (int r = 0; r < 4; r++){
            float v = fmaxf(fmaxf(z0[r], z1[r]), fmaxf(z2[r], z3[r]));
            v = fmaxf(v, __shfl_xor(v, 1));
            v = fmaxf(v, __shfl_xor(v, 2));
            v = fmaxf(v, __shfl_xor(v, 4));
            v = fmaxf(v, __shfl_xor(v, 8));
            float mn = fmaxf(m[r], v);
            al[r] = __builtin_amdgcn_exp2f(m[r] - mn);
            float p0 = __builtin_amdgcn_exp2f(z0[r] - mn);
            float p1 = __builtin_amdgcn_exp2f(z1[r] - mn);
            float p2 = __builtin_amdgcn_exp2f(z2[r] - mn);
            float p3 = __builtin_amdgcn_exp2f(z3[r] - mn);
            lsum[r] = lsum[r]*al[r] + ((p0 + p1) + (p2 + p3));  // lane-partial
            m[r] = mn;
            int row = g*4 + r;
            plds[w][row][ln]      = f2bf(p0);
            plds[w][row][ln + 16] = f2bf(p1);
            plds[w][row][ln + 32] = f2bf(p2);
            plds[w][row][ln + 48] = f2bf(p3);
        }
#pragma unroll
        for (int r = 0; r < 4; r++){
            o0[r] *= al[r]; o1[r] *= al[r]; o2[r] *= al[r]; o3[r] *= al[r];
        }
        asm volatile("s_waitcnt lgkmcnt(0)" ::: "memory");  // cross-lane P write->read
        __builtin_amdgcn_sched_barrier(0);
        s8v pa0 = *(const s8v*)&plds[w][ln][g*8];
        s8v pa1 = *(const s8v*)&plds[w][ln][32 + g*8];
        size_t voff = ((size_t)b*HDIM + ln) * SEQ + s0 + g*8;
        s8v v00 = *(const s8v*)(vt + voff);
        s8v v01 = *(const s8v*)(vt + voff + 32);
        s8v v10 = *(const s8v*)(vt + voff + 16*SEQ);
        s8v v11 = *(const s8v*)(vt + voff + 16*SEQ + 32);
        s8v v20 = *(const s8v*)(vt + voff + 32*SEQ);
        s8v v21 = *(const s8v*)(vt + voff + 32*SEQ + 32);
        s8v v30 = *(const s8v*)(vt + voff + 48*SEQ);
        s8v v31 = *(const s8v*)(vt + voff + 48*SEQ + 32);
        o0 = MFMA(pa0, v00, o0); o0 = MFMA(pa1, v01, o0);
        o1 = MFMA(pa0, v10, o1); o1 = MFMA(pa1, v11, o1);
        o2 = MFMA(pa0, v20, o2); o2 = MFMA(pa1, v21, o2);
        o3 = MFMA(pa0, v30, o3); o3 = MFMA(pa1, v31, o3);
    }

    // deferred l-sum reduce (off the per-tile critical path)
#pragma unroll
    for (int r = 0; r < 4; r++){
        float s = lsum[r];
        s += __shfl_xor(s, 1);
        s += __shfl_xor(s, 2);
        s += __shfl_xor(s, 4);
        s += __shfl_xor(s, 8);
        lsum[r] = s;
    }

    // ---- write per-wave partials to LDS ----
#pragma unroll
    for (int r = 0; r < 4; r++){
        int row = g*4 + r;
        olds[w][row][ln]      = o0[r];
        olds[w][row][ln + 16] = o1[r];
        olds[w][row][ln + 32] = o2[r];
        olds[w][row][ln + 48] = o3[r];
        if (ln == 0){ mlds[w][row] = m[r]; llds[w][row] = lsum[r]; }
    }
    __syncthreads();

    // ---- combine 4 partials (exact online-softmax merge), coalesced store ----
    {
        int row = tid >> 4;          // 0..15
        int hb  = tid & 15;          // 0..15
        float m0 = mlds[0][row], m1 = mlds[1][row], m2 = mlds[2][row], m3 = mlds[3][row];
        float M = fmaxf(fmaxf(m0, m1), fmaxf(m2, m3));   // finite: wave 0 always has tile 0
        float w0 = __builtin_amdgcn_exp2f(m0 - M);
        float w1 = __builtin_amdgcn_exp2f(m1 - M);
        float w2 = __builtin_amdgcn_exp2f(m2 - M);
        float w3 = __builtin_amdgcn_exp2f(m3 - M);
        float L = llds[0][row]*w0 + llds[1][row]*w1 + llds[2][row]*w2 + llds[3][row]*w3;
        float inv = 1.0f / L;
        size_t obase = ((size_t)b*SEQ + tq + row) * HDIM + hb;
#pragma unroll
        for (int j = 0; j < 4; j++){
            int h = hb + 16*j;
            float acc = olds[0][row][h]*w0 + olds[1][row][h]*w1
                      + olds[2][row][h]*w2 + olds[3][row][h]*w3;
            out[obase + 16*j] = acc * inv;
        }
    }
}

extern "C" void kernel_launch(void* const* d_in, const int* in_sizes, int n_in,
                              void* d_out, int out_size, void* d_ws, size_t ws_size,
                              hipStream_t stream) {
    (void)in_sizes; (void)n_in; (void)out_size; (void)ws_size;
    const float* x  = (const float*)d_in[0];
    const float* wq = (const float*)d_in[1];
    const float* wk = (const float*)d_in[2];
    const float* wv = (const float*)d_in[3];
    float* out = (float*)d_out;

    short* ws  = (short*)d_ws;               // ~7.1 MB total workspace
    short* wtP = ws;                          // packed W: 32*12288 shorts = 768 KB
    short* q   = wtP + (size_t)NKS*STEPSH;
    short* k   = q + (size_t)BT*HDIM;
    short* vt  = k + (size_t)BT*HDIM;

    prep_w_kernel<<<NCAT, 256, 0, stream>>>(wq, wk, wv, wtP);
    proj_kernel<<<BT/64, 512, 0, stream>>>(x, wtP, q, k, vt);
    attn_kernel<<<dim3(SEQ/16, BATCH), 256, 0, stream>>>(q, k, vt, out);
}